// Round 5
// baseline (526.702 us; speedup 1.0000x reference)
//
#include <hip/hip_runtime.h>
#include <stdint.h>

// Problem constants
#define BATCH 32
#define C_IN 192
#define T_DIM 256
#define V_N 21
#define HEADS 3
#define C_OUTD 192
#define NPROJ 576        // HEADS*C_OUT
#define NEG_SLOPE 0.2f
#define W_ELEMS (NPROJ * C_IN)   // 110592
#define WF_BLOCKS 432            // W_ELEMS / 256

typedef __attribute__((ext_vector_type(8))) short short8;
typedef __attribute__((ext_vector_type(4))) float f32x4;

// ---- LDS layout (bytes) ----
// projb overlaps the (dead-after-GEMM) xs staging region.
#define XS_LD 200                        // shorts per xs row (32 rows read, 21 valid)
#define PROJB_LD 600                     // shorts per projb row (576 + 24 pad)
#define PROJB_BYTES (21 * PROJB_LD * 2)  // 25200
#define ATTN2_OFF 25216                  // 16B aligned
#define ATTN2_LD 40                      // shorts
#define SS_OFF (ATTN2_OFF + HEADS * 16 * ATTN2_LD * 2)  // 25216+3840 = 29056
#define LDS_TOTAL (SS_OFF + 512)         // 29568

__device__ __forceinline__ unsigned short f2bf(float f) {
    uint32_t u = __float_as_uint(f);
    u += 0x7fffu + ((u >> 16) & 1u);   // RNE (inputs are finite)
    return (unsigned short)(u >> 16);
}
__device__ __forceinline__ float bf2f(unsigned short h) {
    return __uint_as_float(((uint32_t)h) << 16);
}

// Blocks 0..431: W (float [576][192]) -> Wf (bf16, MFMA B-fragment order):
//   Wf[((nt*6+ks)*64 + lane)*8 + j] = W[nt*16 + (lane&15)][ks*32 + (lane>>4)*8 + j]
// Blocks 432..434 (h = blk-432): score-fused tile nt=36:
//   col h   = wsrc[h][k] = sum_c W[h*192+c][k] * ssrc[h][c]
//   col 3+h = wtgt[h][k]   (cols 6..15 left garbage -> their acc cols are never read)
__global__ void convert_kernel(const float* __restrict__ W,
                               const float* __restrict__ ssrc,
                               const float* __restrict__ stgt,
                               unsigned short* __restrict__ Wf) {
    if (blockIdx.x < WF_BLOCKS) {
        int o = blockIdx.x * 256 + threadIdx.x;   // 0..110591
        int j    = o & 7;
        int lane = (o >> 3) & 63;
        int p    = o >> 9;            // 0..215
        int ks   = p % 6;
        int nt   = p / 6;             // 0..35
        int n = nt * 16 + (lane & 15);
        int k = ks * 32 + (lane >> 4) * 8 + j;
        Wf[o] = f2bf(W[n * C_IN + k]);
    } else {
        int h = blockIdx.x - WF_BLOCKS;
        int k = threadIdx.x;
        if (k < C_IN) {
            float ws = 0.f, wt = 0.f;
#pragma unroll 4
            for (int co = 0; co < C_OUTD; co++) {
                float w = W[(h * C_OUTD + co) * C_IN + k];
                ws += w * ssrc[h * C_OUTD + co];
                wt += w * stgt[h * C_OUTD + co];
            }
            int ks = k >> 5;
            int r  = (k >> 3) & 3;
            int j  = k & 7;
            Wf[(((36 * 6 + ks) * 64) + r * 16 + h) * 8 + j]     = f2bf(ws);
            Wf[(((36 * 6 + ks) * 64) + r * 16 + 3 + h) * 8 + j] = f2bf(wt);
        }
    }
}

// (512, 6): r4 sat at 88 unified regs (52 arch + 36 acc) -> 5 waves/SIMD -> only
// 2 blocks/CU (50% occ, achieved 45%). Capping at 6 waves/EU (<=85 -> 80 regs)
// unlocks 3 blocks/CU (75%). Unlike r1/r2 (58+ reg squeeze -> acc spilled), this
// is an 8-reg squeeze against ~50 regs of prefetch/staging slack. Phase A's load
// batch is split 8->4+4 to hand the allocator 4 of those regs directly.
// ABORT criterion: hbm_bytes > 3.1e8 or VGPR collapse => cap spilled, revert.
__global__ __launch_bounds__(512, 6)
void gat_fused_kernel(const float* __restrict__ x,
                      const float* __restrict__ A,
                      const unsigned short* __restrict__ Wf,
                      float* __restrict__ out) {
    __shared__ __align__(16) char lds[LDS_TOTAL];
    unsigned short* xs    = (unsigned short*)lds;               // [32][XS_LD] (21 valid rows)
    unsigned short* projb = (unsigned short*)lds;               // alias (xs dead after GEMM reads)
    unsigned short* attn2 = (unsigned short*)(lds + ATTN2_OFF); // [3][16][ATTN2_LD]
    float* ssl = (float*)(lds + SS_OFF);        // [63]
    float* stl = (float*)(lds + SS_OFF + 256);  // [63]

    const int tid  = threadIdx.x;
    const int wv   = tid >> 6;          // 0..7
    const int lane = tid & 63;
    const int q    = lane >> 4;
    const int l15  = lane & 15;
    const int wn   = wv & 3;            // col group (144 cols)
    const int wm   = wv >> 2;           // m-half (rows wm*16 .. wm*16+15)
    const int bp   = blockIdx.x;        // bp = b*T + t
    const int b    = bp >> 8;
    const int t    = bp & 255;

    // ---- Phase A: stage x slice -> bf16 LDS (504 threads, 2 batches of 4 strided loads)
    const float* xb = x + (size_t)b * (C_IN * T_DIM * V_N) + (size_t)t * V_N;
    if (tid < 504) {
        int c0 = tid / 21;              // 0..23
        int v  = tid - c0 * 21;         // 0..20
        const float* p = xb + (size_t)c0 * (T_DIM * V_N) + v;
        unsigned short* xrow = xs + v * XS_LD + c0;
        float xr[4];
#pragma unroll
        for (int k = 0; k < 4; k++) xr[k] = p[(size_t)k * (24 * T_DIM * V_N)];
#pragma unroll
        for (int k = 0; k < 4; k++) xrow[24 * k] = f2bf(xr[k]);
#pragma unroll
        for (int k = 4; k < 8; k++) xr[k - 4] = p[(size_t)k * (24 * T_DIM * V_N)];
#pragma unroll
        for (int k = 4; k < 8; k++) xrow[24 * k] = f2bf(xr[k - 4]);
    }
    __syncthreads();   // bar1

    // ---- Phase B: GEMM proj = xs(21x192, m-pad 32) @ W^T(192x576)
    // wave (wm,wn) owns rows [wm*16,wm*16+16) x cols [wn*144,wn*144+144): 9 tiles.
    f32x4 acc[9];
#pragma unroll
    for (int nt = 0; nt < 9; nt++) acc[nt] = (f32x4){0.f, 0.f, 0.f, 0.f};

    const int colbase = wn * 144 + l15;
    const int arow = (wm * 16 + l15) * XS_LD;
    const unsigned short* wf0 = Wf + ((size_t)(wn * 9) * 6) * 512 + lane * 8;
#pragma unroll
    for (int ks = 0; ks < 6; ks++) {
        const int koff = ks * 32 + q * 8;
        short8 a = *(const short8*)(xs + arow + koff);   // wm=1 rows>=21 garbage; rows discarded
#pragma unroll
        for (int nt = 0; nt < 9; nt++) {
            short8 bfr = *(const short8*)(wf0 + (nt * 6 + ks) * 512);
            acc[nt] = __builtin_amdgcn_mfma_f32_16x16x32_bf16(a, bfr, acc[nt], 0, 0, 0);
        }
    }

    // ---- Score tile: wave 3 covers m0 rows (0..15), wave 7 covers m1 rows (16..20).
    // cols 0..2 = ss[h], cols 3..5 = st[h]; cols 6..15 garbage (never read).
    if (wv == 3 || wv == 7) {
        f32x4 as = (f32x4){0.f, 0.f, 0.f, 0.f};
        const unsigned short* wfs = Wf + (size_t)(36 * 6) * 512 + lane * 8;
#pragma unroll
        for (int ks = 0; ks < 6; ks++) {
            short8 a = *(const short8*)(xs + arow + ks * 32 + q * 8);
            short8 bs = *(const short8*)(wfs + ks * 512);
            as = __builtin_amdgcn_mfma_f32_16x16x32_bf16(a, bs, as, 0, 0, 0);
        }
        if (l15 < 6) {   // ss/st region is disjoint from xs -> safe before bar2
            float* dst = (l15 < 3) ? ssl : stl;
            int h = (l15 < 3) ? l15 : l15 - 3;
#pragma unroll
            for (int r = 0; r < 4; r++) {
                int v0 = wm * 16 + q * 4 + r;
                if (v0 < 21) dst[v0 * 3 + h] = as[r];
            }
        }
    }
    __syncthreads();   // bar2: all xs reads complete -> projb may overwrite

    // ---- Epilogue: acc -> projb bf16 (21 rows only)
#pragma unroll
    for (int nt = 0; nt < 9; nt++) {
        const int col = colbase + nt * 16;
#pragma unroll
        for (int r = 0; r < 4; r++) {
            int row = wm * 16 + q * 4 + r;
            if (row < 21) projb[row * PROJB_LD + col] = f2bf(acc[nt][r]);
        }
    }

    // ---- Phase D+E merged: masked softmax + skip-mean 3-row fold, wave h handles head h.
    // Rows i,i+1,i+2 live in adjacent lanes -> fold via shfl_down. attn2 rows m>=7 left
    // garbage (their MFMA output rows are discarded); cols 21..31 of valid rows zeroed.
    if (wv < 3 && lane < 21) {
        const int h = wv, i = lane;
        const float* Ah = A + (h * 21 + i) * 21;
        float si = ssl[i * 3 + h];
        float vals[21];
        float mx = -1e30f;
#pragma unroll
        for (int j = 0; j < 21; j++) {
            float a = Ah[j];
            float z = si + stl[j * 3 + h];
            float e = (z > 0.f) ? z : NEG_SLOPE * z;
            float val = (a != 0.f) ? (e + a) : -1e30f;
            vals[j] = val;
            mx = fmaxf(mx, val);
        }
        float sum = 0.f;
#pragma unroll
        for (int j = 0; j < 21; j++) {
            float e = __expf(vals[j] - mx);
            vals[j] = e;
            sum += e;
        }
        float inv = 1.f / sum;
        int m = i / 3;
        bool wr = (i == m * 3);   // writer lanes: i = 0,3,...,18 (only read lanes <= 20)
        unsigned short* drow = attn2 + (h * 16 + m) * ATTN2_LD;
#pragma unroll
        for (int j = 0; j < 21; j++) {
            float vv = vals[j] * inv;
            float s = vv + __shfl_down(vv, 1) + __shfl_down(vv, 2);
            if (wr) drow[j] = f2bf(s);
        }
        if (wr) {
#pragma unroll
            for (int j = 21; j < 32; j++) drow[j] = 0;
        }
    }
    __syncthreads();   // bar3

    // ---- Phase F: agg2[h] = attn2[h](7x21 pad 16x32) @ nf[h](21x192) via MFMA, epilogue fused.
    // 36 (h,nt) tiles over 8 waves: waves 0..3 take 5, waves 4..7 take 4.
    float* outb = out + (size_t)bp * (V_N * C_OUTD);
    int rw[8];
#pragma unroll
    for (int j = 0; j < 8; j++) {
        int row = q * 8 + j;
        rw[j] = ((row > 20) ? 20 : row) * PROJB_LD;   // clamp: attn2 k-cols >=21 are zero
    }
#pragma unroll
    for (int i = 0; i < 5; i++) {
        int p = wv + 8 * i;
        if (p < 36) {
            int h = p / 12;
            int nt = p - h * 12;
            int colh = nt * 16 + l15;            // col within head's 192
            int col = h * C_OUTD + colh;         // col within projb's 576
            short8 bfr;
#pragma unroll
            for (int j = 0; j < 8; j++) bfr[j] = (short)projb[rw[j] + col];
            short8 av = *(const short8*)(attn2 + (h * 16 + l15) * ATTN2_LD + q * 8);
            f32x4 z = (f32x4){0.f, 0.f, 0.f, 0.f};
            f32x4 d = __builtin_amdgcn_mfma_f32_16x16x32_bf16(av, bfr, z, 0, 0, 0);
#pragma unroll
            for (int r = 0; r < 4; r++) {
                int m = q * 4 + r;
                if (m < 7) {
                    int k = h * 7 + m;
                    float skip = bf2f(projb[k * PROJB_LD + colh])
                               + bf2f(projb[k * PROJB_LD + C_OUTD + colh])
                               + bf2f(projb[k * PROJB_LD + 2 * C_OUTD + colh]);
                    outb[k * C_OUTD + colh] = (d[r] + skip) * (1.f / 3.f);
                }
            }
        }
    }
}

extern "C" void kernel_launch(void* const* d_in, const int* in_sizes, int n_in,
                              void* d_out, int out_size, void* d_ws, size_t ws_size,
                              hipStream_t stream) {
    (void)in_sizes; (void)n_in; (void)out_size; (void)ws_size;
    const float* x    = (const float*)d_in[0];
    const float* A    = (const float*)d_in[1];
    const float* W    = (const float*)d_in[2];
    const float* ssrc = (const float*)d_in[3];
    const float* stgt = (const float*)d_in[4];
    float* out = (float*)d_out;
    unsigned short* Wf = (unsigned short*)d_ws;   // 37 tiles * 6 * 512 * 2B = 227,328 bytes

    convert_kernel<<<WF_BLOCKS + HEADS, 256, 0, stream>>>(W, ssrc, stgt, Wf);
    gat_fused_kernel<<<BATCH * T_DIM, 512, 0, stream>>>(x, A, Wf, out);
}

// Round 6
// 448.430 us; speedup vs baseline: 1.1745x; 1.1745x over previous
//
#include <hip/hip_runtime.h>
#include <stdint.h>

// Problem constants
#define BATCH 32
#define C_IN 192
#define T_DIM 256
#define V_N 21
#define HEADS 3
#define C_OUTD 192
#define NPROJ 576        // HEADS*C_OUT
#define NEG_SLOPE 0.2f
#define W_ELEMS (NPROJ * C_IN)   // 110592
#define WF_BLOCKS 432            // W_ELEMS / 256

typedef __attribute__((ext_vector_type(8))) short short8;
typedef __attribute__((ext_vector_type(4))) float f32x4;

// ---- LDS layout (bytes) ----
// projb overlaps the xs staging region. projb rows 16..20 start at byte
// 16*1200=19200 > XS_BYTES(12800), so the m1 epilogue may be written while xs
// is still live; only rows 0..15 (m0 epilogue) must wait for bar2.
#define XS_LD 200                        // shorts per xs row (21 valid rows, 12800 B)
#define PROJB_LD 600                     // shorts per projb row (576 + 24 pad)
#define PROJB_BYTES (21 * PROJB_LD * 2)  // 25200
#define ATTN2_OFF 25216                  // 16B aligned
#define ATTN2_LD 40                      // shorts
#define SS_OFF (ATTN2_OFF + HEADS * 16 * ATTN2_LD * 2)  // 25216+3840 = 29056
#define LDS_TOTAL (SS_OFF + 512)         // 29568 -> 5 blocks/CU by LDS

__device__ __forceinline__ unsigned short f2bf(float f) {
    uint32_t u = __float_as_uint(f);
    u += 0x7fffu + ((u >> 16) & 1u);   // RNE (inputs are finite)
    return (unsigned short)(u >> 16);
}
__device__ __forceinline__ float bf2f(unsigned short h) {
    return __uint_as_float(((uint32_t)h) << 16);
}

// Blocks 0..431: W (float [576][192]) -> Wf (bf16, MFMA B-fragment order):
//   Wf[((nt*6+ks)*64 + lane)*8 + j] = W[nt*16 + (lane&15)][ks*32 + (lane>>4)*8 + j]
// Blocks 432..434 (h = blk-432): score-fused tile nt=36:
//   col h   = wsrc[h][k] = sum_c W[h*192+c][k] * ssrc[h][c]
//   col 3+h = wtgt[h][k]   (cols 6..15 left garbage -> their acc cols are never read)
__global__ void convert_kernel(const float* __restrict__ W,
                               const float* __restrict__ ssrc,
                               const float* __restrict__ stgt,
                               unsigned short* __restrict__ Wf) {
    if (blockIdx.x < WF_BLOCKS) {
        int o = blockIdx.x * 256 + threadIdx.x;   // 0..110591
        int j    = o & 7;
        int lane = (o >> 3) & 63;
        int p    = o >> 9;            // 0..215
        int ks   = p % 6;
        int nt   = p / 6;             // 0..35
        int n = nt * 16 + (lane & 15);
        int k = ks * 32 + (lane >> 4) * 8 + j;
        Wf[o] = f2bf(W[n * C_IN + k]);
    } else {
        int h = blockIdx.x - WF_BLOCKS;
        int k = threadIdx.x;
        if (k < C_IN) {
            float ws = 0.f, wt = 0.f;
#pragma unroll 4
            for (int co = 0; co < C_OUTD; co++) {
                float w = W[(h * C_OUTD + co) * C_IN + k];
                ws += w * ssrc[h * C_OUTD + co];
                wt += w * stgt[h * C_OUTD + co];
            }
            int ks = k >> 5;
            int r  = (k >> 3) & 3;
            int j  = k & 7;
            Wf[(((36 * 6 + ks) * 64) + r * 16 + h) * 8 + j]     = f2bf(ws);
            Wf[(((36 * 6 + ks) * 64) + r * 16 + 3 + h) * 8 + j] = f2bf(wt);
        }
    }
}

// 256-thread / 4-wave geometry: per-wave acc stays 36 regs (9 tiles), but each
// wave covers BOTH m-halves sequentially (m1 first, reusing acc). Natural
// allocation ~88 unified regs -> 5 waves/SIMD; with 1 wave/SIMD per block that
// is 5 blocks/CU (62.5% static) vs r4's 2 (512-thr packed 2 waves/SIMD ->
// floor(5/2)=2 blocks). NO launch-bounds cap: r1/r2/r5 all showed any cap at or
// below natural allocation spills the whole acc array (+0.5..0.7 GB traffic).
__global__ __launch_bounds__(256)
void gat_fused_kernel(const float* __restrict__ x,
                      const float* __restrict__ A,
                      const unsigned short* __restrict__ Wf,
                      float* __restrict__ out) {
    __shared__ __align__(16) char lds[LDS_TOTAL];
    unsigned short* xs    = (unsigned short*)lds;               // [32][XS_LD] (21 valid rows)
    unsigned short* projb = (unsigned short*)lds;               // alias (see layout note)
    unsigned short* attn2 = (unsigned short*)(lds + ATTN2_OFF); // [3][16][ATTN2_LD]
    float* ssl = (float*)(lds + SS_OFF);        // [63]
    float* stl = (float*)(lds + SS_OFF + 256);  // [63]

    const int tid  = threadIdx.x;
    const int wv   = tid >> 6;          // 0..3
    const int lane = tid & 63;
    const int q    = lane >> 4;
    const int l15  = lane & 15;
    const int bp   = blockIdx.x;        // bp = b*T + t
    const int b    = bp >> 8;
    const int t    = bp & 255;

    // ---- Phase A: stage x slice -> bf16 LDS (252 threads, 2 batches of 8 strided loads)
    const float* xb = x + (size_t)b * (C_IN * T_DIM * V_N) + (size_t)t * V_N;
    if (tid < 252) {
        int c0 = tid / 21;              // 0..11
        int v  = tid - c0 * 21;         // 0..20
        const float* p = xb + (size_t)c0 * (T_DIM * V_N) + v;
        unsigned short* xrow = xs + v * XS_LD + c0;
        float xr[8];
#pragma unroll
        for (int k = 0; k < 8; k++) xr[k] = p[(size_t)k * (12 * T_DIM * V_N)];
#pragma unroll
        for (int k = 0; k < 8; k++) xrow[12 * k] = f2bf(xr[k]);
#pragma unroll
        for (int k = 8; k < 16; k++) xr[k - 8] = p[(size_t)k * (12 * T_DIM * V_N)];
#pragma unroll
        for (int k = 8; k < 16; k++) xrow[12 * k] = f2bf(xr[k - 8]);
    }
    __syncthreads();   // bar1

    // ---- Phase B: GEMM proj = xs(21x192, m-pad 32) @ W^T(192x576)
    // wave wv owns cols [wv*144, +144) = 9 n-tiles; m-halves run sequentially
    // (m1 FIRST: its projb rows 16..20 don't alias xs, so no barrier needed).
    const int colbase = wv * 144 + l15;
    const unsigned short* wf0 = Wf + ((size_t)(wv * 9) * 6) * 512 + lane * 8;
    const unsigned short* wfs = Wf + (size_t)(36 * 6) * 512 + lane * 8;

    f32x4 acc[9];

    // ---- B1: m=1 (rows 16..31, valid 16..20)
#pragma unroll
    for (int nt = 0; nt < 9; nt++) acc[nt] = (f32x4){0.f, 0.f, 0.f, 0.f};
    {
        const int arow = (16 + l15) * XS_LD;
#pragma unroll
        for (int ks = 0; ks < 6; ks++) {
            short8 a = *(const short8*)(xs + arow + ks * 32 + q * 8);  // rows>=21 garbage; discarded
#pragma unroll
            for (int nt = 0; nt < 9; nt++) {
                short8 bfr = *(const short8*)(wf0 + (nt * 6 + ks) * 512);
                acc[nt] = __builtin_amdgcn_mfma_f32_16x16x32_bf16(a, bfr, acc[nt], 0, 0, 0);
            }
        }
        // score tile m1 (wave 3): cols 0..2 = ss[h], 3..5 = st[h]
        if (wv == 3) {
            f32x4 as = (f32x4){0.f, 0.f, 0.f, 0.f};
#pragma unroll
            for (int ks = 0; ks < 6; ks++) {
                short8 a = *(const short8*)(xs + arow + ks * 32 + q * 8);
                short8 bs = *(const short8*)(wfs + ks * 512);
                as = __builtin_amdgcn_mfma_f32_16x16x32_bf16(a, bs, as, 0, 0, 0);
            }
            if (l15 < 6) {   // ss/st region disjoint from xs
                float* dst = (l15 < 3) ? ssl : stl;
                int h = (l15 < 3) ? l15 : l15 - 3;
#pragma unroll
                for (int r = 0; r < 4; r++) {
                    int v1 = 16 + q * 4 + r;
                    if (v1 < 21) dst[v1 * 3 + h] = as[r];
                }
            }
        }
        // epilogue m1 -> projb rows 16..20 (byte offsets >= 19200 > 12800: no xs clash)
#pragma unroll
        for (int nt = 0; nt < 9; nt++) {
            const int col = colbase + nt * 16;
#pragma unroll
            for (int r = 0; r < 4; r++) {
                int row = 16 + q * 4 + r;
                if (row < 21) projb[row * PROJB_LD + col] = f2bf(acc[nt][r]);
            }
        }
    }

    // ---- B2: m=0 (rows 0..15), reuse acc registers
#pragma unroll
    for (int nt = 0; nt < 9; nt++) acc[nt] = (f32x4){0.f, 0.f, 0.f, 0.f};
    {
        const int arow = l15 * XS_LD;
#pragma unroll
        for (int ks = 0; ks < 6; ks++) {
            short8 a = *(const short8*)(xs + arow + ks * 32 + q * 8);
#pragma unroll
            for (int nt = 0; nt < 9; nt++) {
                short8 bfr = *(const short8*)(wf0 + (nt * 6 + ks) * 512);
                acc[nt] = __builtin_amdgcn_mfma_f32_16x16x32_bf16(a, bfr, acc[nt], 0, 0, 0);
            }
        }
        // score tile m0 (wave 3): rows 0..15 all valid
        if (wv == 3) {
            f32x4 as = (f32x4){0.f, 0.f, 0.f, 0.f};
#pragma unroll
            for (int ks = 0; ks < 6; ks++) {
                short8 a = *(const short8*)(xs + arow + ks * 32 + q * 8);
                short8 bs = *(const short8*)(wfs + ks * 512);
                as = __builtin_amdgcn_mfma_f32_16x16x32_bf16(a, bs, as, 0, 0, 0);
            }
            if (l15 < 6) {
                float* dst = (l15 < 3) ? ssl : stl;
                int h = (l15 < 3) ? l15 : l15 - 3;
#pragma unroll
                for (int r = 0; r < 4; r++) {
                    int v0 = q * 4 + r;
                    dst[v0 * 3 + h] = as[r];
                }
            }
        }
    }
    __syncthreads();   // bar2: ALL xs reads complete -> rows 0..15 of projb may overwrite

    // ---- epilogue m0 -> projb rows 0..15
#pragma unroll
    for (int nt = 0; nt < 9; nt++) {
        const int col = colbase + nt * 16;
#pragma unroll
        for (int r = 0; r < 4; r++) {
            int row = q * 4 + r;   // 0..15, always valid
            projb[row * PROJB_LD + col] = f2bf(acc[nt][r]);
        }
    }

    // ---- Phase D+E merged: masked softmax + skip-mean 3-row fold, wave h handles head h.
    // Rows i,i+1,i+2 live in adjacent lanes -> fold via shfl_down. attn2 rows m>=7 left
    // garbage (their MFMA output rows are discarded); cols 21..31 of valid rows zeroed.
    if (wv < 3 && lane < 21) {
        const int h = wv, i = lane;
        const float* Ah = A + (h * 21 + i) * 21;
        float si = ssl[i * 3 + h];
        float vals[21];
        float mx = -1e30f;
#pragma unroll
        for (int j = 0; j < 21; j++) {
            float a = Ah[j];
            float z = si + stl[j * 3 + h];
            float e = (z > 0.f) ? z : NEG_SLOPE * z;
            float val = (a != 0.f) ? (e + a) : -1e30f;
            vals[j] = val;
            mx = fmaxf(mx, val);
        }
        float sum = 0.f;
#pragma unroll
        for (int j = 0; j < 21; j++) {
            float e = __expf(vals[j] - mx);
            vals[j] = e;
            sum += e;
        }
        float inv = 1.f / sum;
        int m = i / 3;
        bool wr = (i == m * 3);   // writer lanes: i = 0,3,...,18 (only read lanes <= 20)
        unsigned short* drow = attn2 + (h * 16 + m) * ATTN2_LD;
#pragma unroll
        for (int j = 0; j < 21; j++) {
            float vv = vals[j] * inv;
            float s = vv + __shfl_down(vv, 1) + __shfl_down(vv, 2);
            if (wr) drow[j] = f2bf(s);
        }
        if (wr) {
#pragma unroll
            for (int j = 21; j < 32; j++) drow[j] = 0;
        }
    }
    __syncthreads();   // bar3

    // ---- Phase F: agg2[h] = attn2[h](7x21 pad 16x32) @ nf[h](21x192) via MFMA, epilogue fused.
    // 36 (h,nt) tiles over 4 waves: 9 each.
    float* outb = out + (size_t)bp * (V_N * C_OUTD);
    int rw[8];
#pragma unroll
    for (int j = 0; j < 8; j++) {
        int row = q * 8 + j;
        rw[j] = ((row > 20) ? 20 : row) * PROJB_LD;   // clamp: attn2 k-cols >=21 are zero
    }
#pragma unroll
    for (int i = 0; i < 9; i++) {
        int p = wv * 9 + i;
        int h = p / 12;
        int nt = p - h * 12;
        int colh = nt * 16 + l15;            // col within head's 192
        int col = h * C_OUTD + colh;         // col within projb's 576
        short8 bfr;
#pragma unroll
        for (int j = 0; j < 8; j++) bfr[j] = (short)projb[rw[j] + col];
        short8 av = *(const short8*)(attn2 + (h * 16 + l15) * ATTN2_LD + q * 8);
        f32x4 z = (f32x4){0.f, 0.f, 0.f, 0.f};
        f32x4 d = __builtin_amdgcn_mfma_f32_16x16x32_bf16(av, bfr, z, 0, 0, 0);
#pragma unroll
        for (int r = 0; r < 4; r++) {
            int m = q * 4 + r;
            if (m < 7) {
                int k = h * 7 + m;
                float skip = bf2f(projb[k * PROJB_LD + colh])
                           + bf2f(projb[k * PROJB_LD + C_OUTD + colh])
                           + bf2f(projb[k * PROJB_LD + 2 * C_OUTD + colh]);
                outb[k * C_OUTD + colh] = (d[r] + skip) * (1.f / 3.f);
            }
        }
    }
}

extern "C" void kernel_launch(void* const* d_in, const int* in_sizes, int n_in,
                              void* d_out, int out_size, void* d_ws, size_t ws_size,
                              hipStream_t stream) {
    (void)in_sizes; (void)n_in; (void)out_size; (void)ws_size;
    const float* x    = (const float*)d_in[0];
    const float* A    = (const float*)d_in[1];
    const float* W    = (const float*)d_in[2];
    const float* ssrc = (const float*)d_in[3];
    const float* stgt = (const float*)d_in[4];
    float* out = (float*)d_out;
    unsigned short* Wf = (unsigned short*)d_ws;   // 37 tiles * 6 * 512 * 2B = 227,328 bytes

    convert_kernel<<<WF_BLOCKS + HEADS, 256, 0, stream>>>(W, ssrc, stgt, Wf);
    gat_fused_kernel<<<BATCH * T_DIM, 256, 0, stream>>>(x, A, Wf, out);
}